// Round 6
// baseline (145.969 us; speedup 1.0000x reference)
//
#include <hip/hip_runtime.h>
#include <hip/hip_bf16.h>
#include <hip/hip_cooperative_groups.h>

namespace cg = cooperative_groups;

#define BN 512   // batch
#define DD 512   // feature dim
#define LL 24    // label dim

typedef __attribute__((ext_vector_type(8))) short short8;  // 8 bf16 = 4 VGPR
typedef __attribute__((ext_vector_type(4))) float f32x4;

// ws layout (float words):
//   [0,512)              masks (u32)
//   [512, 512+262144)    Dm (f32, 512x512)
//   [262656 + {0,1,2}]   accum: sum(f32), cnt(u32), ticket(u32)

__device__ __forceinline__ float dist_val(float d2, bool diag) {
    d2 = fmaxf(d2, 0.0f);
    float d = sqrtf(d2);
    return diag ? 0.0f : d;
}

__device__ __forceinline__ unsigned pk_bf16(float lo, float hi) {
    __hip_bfloat162 p = __float22bfloat162_rn(make_float2(lo, hi));
    unsigned u;
    __builtin_memcpy(&u, &p, 4);     // type-pun; bit_cast rejects non-trivial ctor
    return u;
}

// pack 8 f32 -> bf16 fragment via v_cvt_pk_bf16_f32, accumulate sum of squares
__device__ __forceinline__ short8 pack8_pk(float4 x, float4 y, float& nrm) {
    nrm = fmaf(x.x, x.x, nrm); nrm = fmaf(x.y, x.y, nrm);
    nrm = fmaf(x.z, x.z, nrm); nrm = fmaf(x.w, x.w, nrm);
    nrm = fmaf(y.x, y.x, nrm); nrm = fmaf(y.y, y.y, nrm);
    nrm = fmaf(y.z, y.z, nrm); nrm = fmaf(y.w, y.w, nrm);
    union { uint4 u; short8 s; } cv;
    cv.u.x = pk_bf16(x.x, x.y);
    cv.u.y = pk_bf16(x.z, x.w);
    cv.u.z = pk_bf16(y.x, y.y);
    cv.u.w = pk_bf16(y.z, y.w);
    return cv.s;
}

// ---------------- single cooperative kernel ----------------------------------
// Phase 1 (all 1024 blocks, 1 wave each): R0-verified dist kernel, verbatim.
//   Block (bx,by) = (blockIdx&31, blockIdx>>5) computes the 16x16 tile
//   Dm[by*16.., bx*16..]; by==0 blocks also build label masks; block 0 zeros
//   accum/ticket.
// grid.sync(): Dm, masks, accum init visible device-wide.
// Phase 2 (blocks 0..511, 1 wave each): R2-verified sparse triplet row.
//   Register-resident masks; ballot positives; rows with no negative exit
//   early (P(neg pair) = (3/4)^24 ~ 0.001 -> ~60% of rows). Partials
//   atomicAdd'd; last-done block (ticket) writes out. Blocks 512..1023 exit.
__global__ __launch_bounds__(64) void fused_all(
    const float* __restrict__ S, const int* __restrict__ labels,
    unsigned* __restrict__ masks, float* __restrict__ Dm, float* __restrict__ accum,
    float* __restrict__ out)
{
    const int l  = threadIdx.x;
    const int bx = blockIdx.x & 31;
    const int by = blockIdx.x >> 5;

    // ================= phase 1: distance tile (R0 verbatim) =================
    {
        const int r    = l & 15;        // fragment row (A.m / B.n), also C.col
        const int half = l >> 4;        // k-base half*8; C.row base half*4
        const int jb = bx * 16;
        const int ib = by * 16;
        const int kb = half * 8;

        if (by == 0) {
            if (l < 16) {
                const int row = bx * 16 + l;
                const int* lab = labels + row * LL;
                unsigned m = 0;
#pragma unroll
                for (int q = 0; q < LL; q++) m |= (lab[q] != 0 ? 1u : 0u) << q;
                masks[row] = m;
            }
            if (bx == 0 && l == 0) {
                accum[0] = 0.0f;
                ((unsigned*)accum)[1] = 0u;
                ((unsigned*)accum)[2] = 0u;    // ticket
            }
        }

        const float* pA = S + (size_t)(ib + r) * DD + kb;
        const float* pB = S + (size_t)(jb + r) * DD + kb;

        f32x4 acc = {0.f, 0.f, 0.f, 0.f};
        float nA = 0.f, nB = 0.f;

        float4 ax = *(const float4*)pA, ay = *(const float4*)(pA + 4);
        float4 bx4 = *(const float4*)pB, by4 = *(const float4*)(pB + 4);

        for (int k0 = 0; k0 < DD; k0 += 32) {
            float4 nax, nay, nbx, nby;
            const int kn = k0 + 32;
            if (kn < DD) {              // uniform: prefetch next k-step
                nax = *(const float4*)(pA + kn); nay = *(const float4*)(pA + kn + 4);
                nbx = *(const float4*)(pB + kn); nby = *(const float4*)(pB + kn + 4);
            }
            short8 af = pack8_pk(ax, ay, nA);
            short8 bf = pack8_pk(bx4, by4, nB);
            acc = __builtin_amdgcn_mfma_f32_16x16x32_bf16(af, bf, acc, 0, 0, 0);
            ax = nax; ay = nay; bx4 = nbx; by4 = nby;
        }

        // norms: row ib+r covered by lanes {r, r+16, r+32, r+48} (disjoint k)
        nA += __shfl_xor(nA, 16); nA += __shfl_xor(nA, 32);
        nB += __shfl_xor(nB, 16); nB += __shfl_xor(nB, 32);

        // C/D layout (verified): col = lane&15, row = half*4 + reg
        const int jc = jb + r;
        const float nj = nB;
#pragma unroll
        for (int p = 0; p < 4; p++) {
            const int ir = ib + half * 4 + p;
            const float ni = __shfl(nA, half * 4 + p);
            Dm[(size_t)ir * BN + jc] = dist_val(ni + nj - 2.f * acc[p], ir == jc);
        }
    }

    __threadfence();                    // device-scope release of Dm/masks
    cg::this_grid().sync();             // all tiles + masks + accum init visible

    // ================= phase 2: sparse triplet row (R2 verbatim) ============
    const int i = blockIdx.x;
    if (i >= BN) return;                // blocks 512..1023 done

    const int lane = l;
    unsigned m[8];
#pragma unroll
    for (int c = 0; c < 8; c++) m[c] = masks[c * 64 + lane];

    float bsum = 0.f; unsigned bcnt = 0;
    {
        const unsigned mi = masks[i];   // uniform -> scalar load (L2-hot)

        unsigned long long pb[8];
        unsigned long long anyneg = 0ull;
#pragma unroll
        for (int c = 0; c < 8; c++) {
            pb[c] = __ballot((mi & m[c]) != 0u);
            anyneg |= ~pb[c];
        }
        if (anyneg != 0ull) {           // wave-uniform activity test
            const float* drow = Dm + (size_t)i * BN;
            float dv[8];
#pragma unroll
            for (int c = 0; c < 8; c++) dv[c] = drow[c * 64 + lane];

#pragma unroll
            for (int c = 0; c < 8; c++) {
                unsigned long long nb = ~pb[c];
                while (nb) {            // wave-uniform, ~0.5 iters/row avg
                    const int k = __ffsll(nb) - 1;
                    nb &= nb - 1;
                    const float dk = __shfl(dv[c], k);
#pragma unroll
                    for (int c2 = 0; c2 < 8; c2++) {
                        if ((pb[c2] >> lane) & 1ull) {   // lane's j is positive
                            const float v = dv[c2] - dk;
                            bsum += fmaxf(v, 0.0f);
                            bcnt += (v > 1e-16f) ? 1u : 0u;
                        }
                    }
                }
            }
        }
    }

    // wave reduce
#pragma unroll
    for (int off = 32; off > 0; off >>= 1) {
        bsum += __shfl_down(bsum, off);
        bcnt += __shfl_down(bcnt, off);
    }
    if (lane == 0 && (bsum != 0.f || bcnt != 0u)) {
        atomicAdd(&accum[0], bsum);
        atomicAdd(&((unsigned*)accum)[1], bcnt);
    }

    // last-block-done finalize (release fence -> ticket -> acquire fence)
    __threadfence();
    if (lane == 0) {
        const unsigned tk = atomicAdd(&((unsigned*)accum)[2], 1u);
        if (tk == (unsigned)(BN - 1)) {
            __threadfence();
            const float    s = atomicAdd(&accum[0], 0.0f);            // coherent read
            const unsigned c = atomicAdd(&((unsigned*)accum)[1], 0u); // coherent read
            out[0] = s / ((float)c + 1e-16f);
        }
    }
}

extern "C" void kernel_launch(void* const* d_in, const int* in_sizes, int n_in,
                              void* d_out, int out_size, void* d_ws, size_t ws_size,
                              hipStream_t stream) {
    const float* src    = (const float*)d_in[0];
    const int*   labels = (const int*)d_in[1];
    float* ws = (float*)d_ws;
    unsigned* masks = (unsigned*)ws;
    float*    Dm    = ws + BN;
    float*    accum = ws + BN + (size_t)BN * BN;
    float*    outp  = (float*)d_out;

    void* args[] = { (void*)&src, (void*)&labels, (void*)&masks,
                     (void*)&Dm, (void*)&accum, (void*)&outp };
    hipLaunchCooperativeKernel((const void*)fused_all, dim3(32 * 32), dim3(64),
                               args, 0, stream);
}

// Round 7
// 68.813 us; speedup vs baseline: 2.1213x; 2.1213x over previous
//
#include <hip/hip_runtime.h>
#include <hip/hip_bf16.h>

#define BN 512   // batch
#define DD 512   // feature dim
#define LL 24    // label dim

typedef unsigned short u16;
typedef __attribute__((ext_vector_type(8))) short short8;  // 8 bf16 = 4 VGPR
typedef __attribute__((ext_vector_type(4))) float f32x4;

// ws layout (float words):
//   [0,512)              masks (u32)
//   [512, 512+262144)    Dm (f32, 512x512)
//   [262656]             accum: [0]=sum(f32) [1]=cnt(u32)

__device__ __forceinline__ float dist_val(float d2, bool diag) {
    d2 = fmaxf(d2, 0.0f);
    float d = sqrtf(d2);
    return diag ? 0.0f : d;
}

__device__ __forceinline__ unsigned pk_bf16(float lo, float hi) {
    __hip_bfloat162 p = __float22bfloat162_rn(make_float2(lo, hi));
    unsigned u;
    __builtin_memcpy(&u, &p, 4);     // type-pun; bit_cast rejects non-trivial ctor
    return u;
}

// pack 8 f32 -> bf16 fragment via v_cvt_pk_bf16_f32, accumulate sum of squares
__device__ __forceinline__ short8 pack8_pk(float4 x, float4 y, float& nrm) {
    nrm = fmaf(x.x, x.x, nrm); nrm = fmaf(x.y, x.y, nrm);
    nrm = fmaf(x.z, x.z, nrm); nrm = fmaf(x.w, x.w, nrm);
    nrm = fmaf(y.x, y.x, nrm); nrm = fmaf(y.y, y.y, nrm);
    nrm = fmaf(y.z, y.z, nrm); nrm = fmaf(y.w, y.w, nrm);
    union { uint4 u; short8 s; } cv;
    cv.u.x = pk_bf16(x.x, x.y);
    cv.u.y = pk_bf16(x.z, x.w);
    cv.u.z = pk_bf16(y.x, y.y);
    cv.u.w = pk_bf16(y.z, y.w);
    return cv.s;
}

// ---------- kernel 1: fused prep + bf16 MFMA dist, K-split 4 waves/tile ------
// R0 structure, one change: each 16x16 tile is computed by 4 waves (256-thread
// block), wave w covering k in [w*128, w*128+128) -- 4 k-steps instead of 16.
// Grid stays 1024 blocks -> 4096 waves = 4 waves/SIMD (R0 had 1: zero TLP).
// Partial MFMA accumulators (linear in K) and partial norms are combined in
// LDS; wave 0 runs R0's exact epilogue (C layout verified: col=lane&15,
// row=half*4+p), with row norms read from LDS instead of shuffles.
__global__ __launch_bounds__(256) void dist_fused_kernel(
    const float* __restrict__ S, const int* __restrict__ labels,
    unsigned* __restrict__ masks, float* __restrict__ Dm, float* __restrict__ accum)
{
    __shared__ f32x4 accL[4][64];          // per-wave partial accumulators (4 KB)
    __shared__ float nAL[4][16];           // per-wave partial row norms (A)
    __shared__ float nBL[4][16];           // per-wave partial row norms (B)

    const int t    = threadIdx.x;
    const int lane = t & 63;
    const int w    = t >> 6;        // wave 0..3 = k-quarter
    const int r    = lane & 15;     // fragment row (A.m / B.n), also C.col
    const int half = lane >> 4;     // k-sub-base half*8; C.row base half*4
    const int jb = blockIdx.x * 16;
    const int ib = blockIdx.y * 16;
    const int kb = w * 128 + half * 8;

    // masks (y==0 blocks, 16 rows each) + accum zero (block 0,0) -- R0 verbatim
    if (blockIdx.y == 0) {
        if (t < 16) {
            const int row = blockIdx.x * 16 + t;
            const int* lab = labels + row * LL;
            unsigned m = 0;
#pragma unroll
            for (int q = 0; q < LL; q++) m |= (lab[q] != 0 ? 1u : 0u) << q;
            masks[row] = m;
        }
        if (blockIdx.x == 0 && t == 0) { accum[0] = 0.0f; ((unsigned*)accum)[1] = 0u; }
    }

    const float* pA = S + (size_t)(ib + r) * DD + kb;
    const float* pB = S + (size_t)(jb + r) * DD + kb;

    f32x4 acc = {0.f, 0.f, 0.f, 0.f};
    float nA = 0.f, nB = 0.f;

    float4 ax = *(const float4*)pA, ay = *(const float4*)(pA + 4);
    float4 bx = *(const float4*)pB, by = *(const float4*)(pB + 4);

#pragma unroll
    for (int k0 = 0; k0 < 128; k0 += 32) {     // 4 steps: this wave's K-quarter
        float4 nax, nay, nbx, nby;
        const int kn = k0 + 32;
        if (kn < 128) {             // uniform: prefetch next k-step (R0 pattern)
            nax = *(const float4*)(pA + kn); nay = *(const float4*)(pA + kn + 4);
            nbx = *(const float4*)(pB + kn); nby = *(const float4*)(pB + kn + 4);
        }
        short8 af = pack8_pk(ax, ay, nA);
        short8 bf = pack8_pk(bx, by, nB);
        acc = __builtin_amdgcn_mfma_f32_16x16x32_bf16(af, bf, acc, 0, 0, 0);
        ax = nax; ay = nay; bx = nbx; by = nby;
    }

    // intra-wave norm reduce: row r's quarter covered by lanes {r,r+16,r+32,r+48}
    nA += __shfl_xor(nA, 16); nA += __shfl_xor(nA, 32);
    nB += __shfl_xor(nB, 16); nB += __shfl_xor(nB, 32);

    accL[w][lane] = acc;
    if (lane < 16) { nAL[w][lane] = nA; nBL[w][lane] = nB; }
    __syncthreads();
    if (w != 0) return;             // wave 0 finishes the tile

    const f32x4 a0 = accL[0][lane], a1 = accL[1][lane],
                a2 = accL[2][lane], a3 = accL[3][lane];
    f32x4 accT = a0 + a1 + a2 + a3;                       // K-partials, linear
    const float njt = nBL[0][r] + nBL[1][r] + nBL[2][r] + nBL[3][r];

    // C/D layout (verified): col = lane&15, row = half*4 + reg
    const int jc = jb + r;
#pragma unroll
    for (int p = 0; p < 4; p++) {
        const int il = half * 4 + p;                      // local A row
        const int ir = ib + il;
        const float ni = nAL[0][il] + nAL[1][il] + nAL[2][il] + nAL[3][il];
        Dm[(size_t)ir * BN + jc] = dist_val(ni + njt - 2.f * accT[p], ir == jc);
    }
}

// ---------------- kernel 2: triplet (R0-verified ballot compaction) ----------
__global__ void triplet_kernel(const float* __restrict__ Dm, const unsigned* __restrict__ masks,
                               float* __restrict__ accum) {
    __shared__ float pos[BN];
    __shared__ float neg[BN];
    __shared__ int pcnt, ncnt;
    __shared__ float wsum[4];
    __shared__ unsigned wcnt[4];
    const int i = blockIdx.x;
    const int t = threadIdx.x;          // 256
    const int lane = t & 63;
    const int w = t >> 6;
    if (t == 0) { pcnt = 0; ncnt = 0; }
    __syncthreads();
    const unsigned mi = masks[i];
    const float* drow = Dm + (size_t)i * BN;
    const unsigned long long ltmask = (1ull << lane) - 1ull;

    for (int j = t; j < BN; j += 256) {
        float dj = drow[j];
        bool isp = (mi & masks[j]) != 0u;
        unsigned long long bal = __ballot(isp);
        int np = __popcll(bal);
        if (np > 0) {
            int ldr = __ffsll((unsigned long long)bal) - 1;
            int base = 0;
            if (lane == ldr) base = atomicAdd(&pcnt, np);
            base = __shfl(base, ldr);
            if (isp) pos[base + __popcll(bal & ltmask)] = dj;
        }
        unsigned long long nbal = ~bal;
        int nn = 64 - np;
        if (nn > 0) {
            int ldr = __ffsll((unsigned long long)nbal) - 1;
            int base = 0;
            if (lane == ldr) base = atomicAdd(&ncnt, nn);
            base = __shfl(base, ldr);
            if (!isp) neg[base + __popcll(nbal & ltmask)] = dj;
        }
    }
    __syncthreads();

    const int P = pcnt, N = ncnt;
    float sum = 0.f;
    unsigned cnt = 0;
    for (int p = t; p < P; p += 256) {
        float a = pos[p];
        for (int n = 0; n < N; n++) {
            float v = a - neg[n];
            sum += fmaxf(v, 0.0f);
            cnt += (v > 1e-16f) ? 1u : 0u;
        }
    }
#pragma unroll
    for (int off = 32; off > 0; off >>= 1) {
        sum += __shfl_down(sum, off);
        cnt += __shfl_down(cnt, off);
    }
    if (lane == 0) { wsum[w] = sum; wcnt[w] = cnt; }
    __syncthreads();
    if (t == 0) {
        sum = wsum[0] + wsum[1] + wsum[2] + wsum[3];
        cnt = wcnt[0] + wcnt[1] + wcnt[2] + wcnt[3];
        if (sum != 0.f || cnt != 0u) {
            atomicAdd(&accum[0], sum);
            atomicAdd(&((unsigned*)accum)[1], cnt);
        }
    }
}

// ---------------- kernel 3: finalize -----------------------------------------
__global__ void finalize_kernel(const float* __restrict__ accum, float* __restrict__ out) {
    if (threadIdx.x == 0) {
        float s = accum[0];
        float c = (float)((const unsigned*)accum)[1];
        out[0] = s / (c + 1e-16f);
    }
}

extern "C" void kernel_launch(void* const* d_in, const int* in_sizes, int n_in,
                              void* d_out, int out_size, void* d_ws, size_t ws_size,
                              hipStream_t stream) {
    const float* src    = (const float*)d_in[0];
    const int*   labels = (const int*)d_in[1];
    float* ws = (float*)d_ws;
    unsigned* masks = (unsigned*)ws;
    float*    Dm    = ws + BN;
    float*    accum = ws + BN + (size_t)BN * BN;

    hipLaunchKernelGGL(dist_fused_kernel, dim3(32, 32), dim3(256), 0, stream,
                       src, labels, masks, Dm, accum);
    hipLaunchKernelGGL(triplet_kernel,    dim3(BN),     dim3(256), 0, stream,
                       Dm, masks, accum);
    hipLaunchKernelGGL(finalize_kernel,   dim3(1),      dim3(64),  0, stream,
                       accum, (float*)d_out);
}